// Round 2
// 153.781 us; speedup vs baseline: 1.0492x; 1.0492x over previous
//
#include <hip/hip_runtime.h>
#include <hip/hip_bf16.h>

// Problem dims (fixed): B=8, L=128, H=768, R=24
#define BD   8
#define LD   128
#define HD   768
#define RD   24
#define H2D  384
#define NF   1536   // fused N (two heads side by side)
#define WSZ  589824 // 768*768

typedef __attribute__((ext_vector_type(8))) short bf16x8;
typedef __attribute__((ext_vector_type(4))) float f32x4;
typedef _Float16 f16x2 __attribute__((ext_vector_type(2)));

__device__ __forceinline__ short f2bf(float f) {
    __hip_bfloat16 h = __float2bfloat16(f);
    return *reinterpret_cast<short*>(&h);
}

// pack two f32 -> one dword of two f16 (RNE)
__device__ __forceinline__ unsigned int packh2(float a, float b) {
    f16x2 p;
    p[0] = (_Float16)a;
    p[1] = (_Float16)b;
    return __builtin_bit_cast(unsigned int, p);
}

// acc += dot2(relu(a + c), w)  -- packed f16 pair math, f32 accumulate
__device__ __forceinline__ void dstep(float& acc, unsigned int cu, f16x2 a, f16x2 w) {
    f16x2 t = a + __builtin_bit_cast(f16x2, cu);
    f16x2 z = {(_Float16)0.f, (_Float16)0.f};
    t = __builtin_elementwise_max(t, z);
#if __has_builtin(__builtin_amdgcn_fdot2)
    acc = __builtin_amdgcn_fdot2(t, w, acc, false);
#else
    acc += (float)t[0] * (float)w[0] + (float)t[1] * (float)w[1];
#endif
}

// ---------------------------------------------------------------------------
// Launch 1: prep. 793 blocks x 256 threads, flat blockIdx.x:
//   [0,96):    pool
//   [96,120):  biasrel (+ subj/obj bias init on q==96)
//   [120,216): embed fp32 -> bf16 (row-major)
//   [216,792): W 64x64 tile transpose+convert
//   792:       wg16 pack: wg16[d] = pack(W_gc[n], W_gc[n+16]), n=(d&15)+(d>>4)*32
__global__ __launch_bounds__(256) void prep_kernel(
        const float* __restrict__ embed, const float* __restrict__ mask,
        const float* __restrict__ rel_emb, const int* __restrict__ trel,
        const float* __restrict__ W_corr,
        const float* __restrict__ W_sh, const float* __restrict__ b_sh,
        const float* __restrict__ W_oh, const float* __restrict__ b_oh,
        const float* __restrict__ b_st, const float* __restrict__ b_ot,
        const float* __restrict__ W_gc,
        float* __restrict__ pool, float* __restrict__ biasrel,
        unsigned short* __restrict__ embedB, unsigned short* __restrict__ WT,
        unsigned int* __restrict__ wg16,
        float* __restrict__ out_subj, float* __restrict__ out_obj) {
    const int q = blockIdx.x, tid = threadIdx.x;

    if (q < 96) {
        // ---- pool
        const int b = q / 12, c = q % 12;
        __shared__ float mrow[LD];
        __shared__ float msum;
        __shared__ float part[4][64];
        if (tid < LD) mrow[tid] = mask[b * LD + tid];
        __syncthreads();
        if (tid == 0) {
            float s = 0.f;
            for (int l = 0; l < LD; ++l) s += mrow[l];
            msum = s;
        }
        __syncthreads();
        const int lc = tid >> 6, hh = tid & 63;
        const int h = c * 64 + hh;
        float acc = 0.f;
        const float* base = embed + ((size_t)b * LD + lc * 32) * HD + h;
#pragma unroll 8
        for (int i = 0; i < 32; ++i) acc += base[(size_t)i * HD] * mrow[lc * 32 + i];
        part[lc][hh] = acc;
        __syncthreads();
        if (lc == 0)
            pool[b * HD + h] = (part[0][hh] + part[1][hh] + part[2][hh] + part[3][hh]) / msum;
    } else if (q < 120) {
        // ---- biasrel: block c handles 64 cols for ALL 8 batches
        const int c = q - 96;             // 0..23
        __shared__ float reAll[8][HD];    // 24.6 KB
        __shared__ float part[4][8][64];  // 8 KB
        for (int u = tid; u < 8 * HD; u += 256) {
            const int b = u / HD, k = u - b * HD;
            reAll[b][k] = rel_emb[(size_t)trel[b] * HD + k];
        }
        if (c == 0) {
            for (int u = tid; u < 3 * LD * BD; u += 256) {
                const int b = u / (3 * LD), rem = u - b * (3 * LD);
                const int l = rem / 3, t = rem - 3 * l;
                out_subj[(b * LD + l) * 3 + t] = b_st[t];
                out_obj [(b * LD + l) * 3 + t] = b_ot[t];
            }
        }
        __syncthreads();
        const int kc = tid >> 6, nn = tid & 63;
        const int n = c * 64 + nn;
        const float* Wp; int col;
        if (n < HD) { Wp = W_sh; col = n; }
        else        { Wp = W_oh; col = n - HD; }
        float acc[8] = {};
        for (int i = 0; i < 192; ++i) {
            const int k = kc * 192 + i;
            const float w = Wp[(size_t)k * HD + col];
#pragma unroll
            for (int b = 0; b < 8; ++b) acc[b] += reAll[b][k] * w;
        }
#pragma unroll
        for (int b = 0; b < 8; ++b) part[kc][b][nn] = acc[b];
        __syncthreads();
        {
            const float bb = (n < HD) ? b_sh[col] : b_oh[col];
            const int b0 = kc, b1 = kc + 4;
            float s0 = part[0][b0][nn] + part[1][b0][nn] + part[2][b0][nn] + part[3][b0][nn];
            float s1 = part[0][b1][nn] + part[1][b1][nn] + part[2][b1][nn] + part[3][b1][nn];
            biasrel[b0 * NF + n] = s0 + bb;
            biasrel[b1 * NF + n] = s1 + bb;
        }
    } else if (q < 216) {
        // ---- embed convert (row-major): 8192 elems per block
        const int base = (q - 120) * 8192;
#pragma unroll
        for (int it = 0; it < 4; ++it) {
            const int off = base + it * 2048 + tid * 8;
            float4 v0 = *(const float4*)&embed[off];
            float4 v1 = *(const float4*)&embed[off + 4];
            bf16x8 p;
            p[0] = f2bf(v0.x); p[1] = f2bf(v0.y); p[2] = f2bf(v0.z); p[3] = f2bf(v0.w);
            p[4] = f2bf(v1.x); p[5] = f2bf(v1.y); p[6] = f2bf(v1.z); p[7] = f2bf(v1.w);
            *(bf16x8*)&embedB[off] = p;
        }
    } else if (q < 792) {
        // ---- W transpose+convert, one 64x64 tile per block
        const int qq = q - 216;
        const int w = qq / 144, t = qq % 144;
        const int kt = t / 12, nt = t % 12;
        const float* src = (w == 0) ? W_corr
                         : (w == 1) ? W_corr + WSZ
                         : (w == 2) ? W_sh + WSZ
                                    : W_oh + WSZ;
        unsigned short* dst = WT + (size_t)w * WSZ;
        __shared__ float tile[64 * 65];
        const int r = tid >> 2, c4 = (tid & 3) * 16;
#pragma unroll
        for (int i = 0; i < 4; ++i) {
            float4 v = *(const float4*)&src[(size_t)(kt * 64 + r) * HD + nt * 64 + c4 + i * 4];
            tile[r * 65 + c4 + i * 4 + 0] = v.x;
            tile[r * 65 + c4 + i * 4 + 1] = v.y;
            tile[r * 65 + c4 + i * 4 + 2] = v.z;
            tile[r * 65 + c4 + i * 4 + 3] = v.w;
        }
        __syncthreads();
        bf16x8 p0, p1;
#pragma unroll
        for (int j = 0; j < 8; ++j) {
            p0[j] = f2bf(tile[(c4 + j) * 65 + r]);
            p1[j] = f2bf(tile[(c4 + 8 + j) * 65 + r]);
        }
        unsigned short* o = dst + (size_t)(nt * 64 + r) * HD + kt * 64 + c4;
        *(bf16x8*)(o)     = p0;
        *(bf16x8*)(o + 8) = p1;
    } else {
        // ---- wg16 pack (q == 792): 384 entries, 256 threads -> grid-stride
        for (int u = tid; u < 384; u += 256) {
            const int n = (u & 15) + (u >> 4) * 32;
            wg16[u] = packh2(W_gc[n], W_gc[n + 16]);
        }
    }
}

// ---------------------------------------------------------------------------
// Launch 2: biggemm. grid (27, 16), 256 threads. BK=64, register-prefetch pipeline.
//  x < 24: dual MFMA GEMM; x >= 24: relh blocks (48)
//  GEMM0 output: packed f16 pairs (n, n+16) -> AC16[row][768 dwords];
//  C-half (n>=768) gets +b_corr before packing.
__global__ __launch_bounds__(256) void biggemm(
        const unsigned short* __restrict__ embedB,
        const unsigned short* __restrict__ WT,
        const float* __restrict__ biasrel,
        const float* __restrict__ W_st, const float* __restrict__ W_ot,
        const float* __restrict__ pool,
        const float* __restrict__ W_hr, const float* __restrict__ b_hr,
        const float* __restrict__ b_corr,
        unsigned int* __restrict__ AC16, float* __restrict__ out_subj,
        float* __restrict__ out_obj, float* __restrict__ rh) {
    const int tid = threadIdx.x;

    if (blockIdx.x >= 24) {
        const int b = blockIdx.y >> 1;
        const int c = (blockIdx.x - 24) * 2 + (blockIdx.y & 1);
        __shared__ float prow[HD];
        __shared__ float rpart[4][64];
        for (int k = tid; k < HD; k += 256) prow[k] = pool[b * HD + k];
        __syncthreads();
        const int kc = tid >> 6, nn = tid & 63;
        const int n = c * 64 + nn;
        float acc = 0.f;
#pragma unroll 8
        for (int i = 0; i < 192; ++i) {
            const int k = kc * 192 + i;
            acc += prow[k] * W_hr[(size_t)k * H2D + n];
        }
        rpart[kc][nn] = acc;
        __syncthreads();
        if (kc == 0)
            rh[b * H2D + n] = fmaxf(rpart[0][nn] + rpart[1][nn] + rpart[2][nn] + rpart[3][nn] + b_hr[n], 0.f);
        return;
    }

    // stride 76 shorts: fr*38 words mod 32 distinct for fr=0..15 -> conflict-free b128
    __shared__ __align__(16) short As [64][76];
    __shared__ __align__(16) short Bs0[64][76];
    __shared__ __align__(16) short Bs1[64][76];
    __shared__ float partial[64][3];

    const int bn0 = blockIdx.x * 64;
    const int bm0 = blockIdx.y * 64;

    const unsigned short* W0 = (bn0 < HD) ? WT : WT + WSZ;
    const unsigned short* W1 = (bn0 < HD) ? WT + 2 * (size_t)WSZ : WT + 3 * (size_t)WSZ;
    const int col0 = (bn0 < HD) ? bn0 : bn0 - HD;

    if (tid < 192) partial[tid / 3][tid % 3] = 0.f;

    // staging: row = tid>>2 (0..63), kc8 = (tid&3)*8 (+32 second chunk)
    const int row = tid >> 2;
    const int kc8 = (tid & 3) * 8;
    const size_t eaBase = (size_t)(bm0 + row) * HD + kc8;
    const size_t waBase = (size_t)(col0 + row) * HD + kc8;

    const int lane = tid & 63;
    const int wv = tid >> 6;
    const int wm = (wv >> 1) * 32;
    const int wn = (wv & 1) * 32;
    const int fr = lane & 15;
    const int kq = (lane >> 4) * 8;
    const int mq = (lane >> 4) * 4;

    f32x4 c00 = {0.f,0.f,0.f,0.f}, c01 = c00, c10 = c00, c11 = c00;
    f32x4 h00 = c00, h01 = c00, h10 = c00, h11 = c00;

    bf16x8 av0, av1, b0v0, b0v1, b1v0, b1v1;
    // prologue: load K-tile 0 into registers
    {
        av0  = *(const bf16x8*)&embedB[eaBase];
        av1  = *(const bf16x8*)&embedB[eaBase + 32];
        b0v0 = *(const bf16x8*)&W0[waBase];
        b0v1 = *(const bf16x8*)&W0[waBase + 32];
        b1v0 = *(const bf16x8*)&W1[waBase];
        b1v1 = *(const bf16x8*)&W1[waBase + 32];
    }

    for (int kt = 0; kt < 12; ++kt) {
        __syncthreads();
        *(bf16x8*)&As [row][kc8]      = av0;
        *(bf16x8*)&As [row][kc8 + 32] = av1;
        *(bf16x8*)&Bs0[row][kc8]      = b0v0;
        *(bf16x8*)&Bs0[row][kc8 + 32] = b0v1;
        *(bf16x8*)&Bs1[row][kc8]      = b1v0;
        *(bf16x8*)&Bs1[row][kc8 + 32] = b1v1;
        __syncthreads();

        // prefetch next K-tile; latency hides under the MFMAs below
        if (kt < 11) {
            const int k0 = (kt + 1) << 6;
            av0  = *(const bf16x8*)&embedB[eaBase + k0];
            av1  = *(const bf16x8*)&embedB[eaBase + k0 + 32];
            b0v0 = *(const bf16x8*)&W0[waBase + k0];
            b0v1 = *(const bf16x8*)&W0[waBase + k0 + 32];
            b1v0 = *(const bf16x8*)&W1[waBase + k0];
            b1v1 = *(const bf16x8*)&W1[waBase + k0 + 32];
        }

#pragma unroll
        for (int kk = 0; kk < 2; ++kk) {
            const int kx = kq + kk * 32;
            bf16x8 a0 = *(bf16x8*)&As[wm + fr][kx];
            bf16x8 a1 = *(bf16x8*)&As[wm + 16 + fr][kx];
            bf16x8 b0 = *(bf16x8*)&Bs0[wn + fr][kx];
            bf16x8 b1 = *(bf16x8*)&Bs0[wn + 16 + fr][kx];
            bf16x8 d0 = *(bf16x8*)&Bs1[wn + fr][kx];
            bf16x8 d1 = *(bf16x8*)&Bs1[wn + 16 + fr][kx];
            c00 = __builtin_amdgcn_mfma_f32_16x16x32_bf16(a0, b0, c00, 0, 0, 0);
            c01 = __builtin_amdgcn_mfma_f32_16x16x32_bf16(a0, b1, c01, 0, 0, 0);
            c10 = __builtin_amdgcn_mfma_f32_16x16x32_bf16(a1, b0, c10, 0, 0, 0);
            c11 = __builtin_amdgcn_mfma_f32_16x16x32_bf16(a1, b1, c11, 0, 0, 0);
            h00 = __builtin_amdgcn_mfma_f32_16x16x32_bf16(a0, d0, h00, 0, 0, 0);
            h01 = __builtin_amdgcn_mfma_f32_16x16x32_bf16(a0, d1, h01, 0, 0, 0);
            h10 = __builtin_amdgcn_mfma_f32_16x16x32_bf16(a1, d0, h10, 0, 0, 0);
            h11 = __builtin_amdgcn_mfma_f32_16x16x32_bf16(a1, d1, h11, 0, 0, 0);
        }
    }

    // GEMM0 epilogue: pack (col, col+16) pairs from (j=0, j=1) frags in-lane.
    // dword index d = (n&15) + (n>>5)*16; C-half gets +b_corr before pack.
    {
        const int dbase = ((bn0 + wn) >> 5) << 4;
        float bc0 = 0.f, bc1 = 0.f;
        if (bn0 >= HD) {
            bc0 = b_corr[bn0 + wn + fr - HD];
            bc1 = b_corr[bn0 + wn + fr - HD + 16];
        }
#pragma unroll
        for (int i = 0; i < 2; ++i) {
            f32x4 a0 = (i == 0) ? c00 : c10;   // j = 0 frag
            f32x4 a1 = (i == 0) ? c01 : c11;   // j = 1 frag (cols +16)
#pragma unroll
            for (int r = 0; r < 4; ++r) {
                const int mrow = bm0 + wm + i * 16 + mq + r;
                AC16[(size_t)mrow * 768 + dbase + fr] = packh2(a0[r] + bc0, a1[r] + bc1);
            }
        }
    }

    // GEMM1 epilogue: relu(+biasrel), row-dot W_st/W_ot, atomics
    {
        const float* brl = biasrel + (size_t)(bm0 / LD) * NF;
        const float* Wt = (bn0 < HD) ? W_st : W_ot;
        float* op = (bn0 < HD) ? out_subj : out_obj;
        float pt[8][3] = {};
#pragma unroll
        for (int j = 0; j < 2; ++j) {
            const int ncol = bn0 + wn + j * 16 + fr;
            const int ncl = (bn0 < HD) ? ncol : ncol - HD;
            const float wt0 = Wt[ncl * 3 + 0];
            const float wt1 = Wt[ncl * 3 + 1];
            const float wt2 = Wt[ncl * 3 + 2];
            const float bias = brl[ncol];
#pragma unroll
            for (int i = 0; i < 2; ++i) {
                f32x4 a = (i == 0) ? (j == 0 ? h00 : h01) : (j == 0 ? h10 : h11);
#pragma unroll
                for (int r = 0; r < 4; ++r) {
                    const float v = fmaxf(a[r] + bias, 0.f);
                    pt[i * 4 + r][0] += v * wt0;
                    pt[i * 4 + r][1] += v * wt1;
                    pt[i * 4 + r][2] += v * wt2;
                }
            }
        }
#pragma unroll
        for (int mask = 1; mask < 16; mask <<= 1) {
#pragma unroll
            for (int x = 0; x < 8; ++x)
#pragma unroll
                for (int t = 0; t < 3; ++t)
                    pt[x][t] += __shfl_xor(pt[x][t], mask, 64);
        }
        if (fr == 0) {
#pragma unroll
            for (int i = 0; i < 2; ++i)
#pragma unroll
                for (int r = 0; r < 4; ++r)
#pragma unroll
                    for (int t = 0; t < 3; ++t)
                        atomicAdd(&partial[wm + i * 16 + mq + r][t], pt[i * 4 + r][t]);
        }
        __syncthreads();
        if (tid < 192) {
            const int m = tid / 3, t = tid % 3;
            atomicAdd(&op[(size_t)(bm0 + m) * 3 + t], partial[m][t]);
        }
    }
}

// ---------------------------------------------------------------------------
// Launch 3: corres + stage1. grid (33, 8), 512 threads.
//  blockIdx.x < 32: xt = x>>1 (8 C-rows), yg = x&1 (64 A-rows, lane = y).
//  8 waves = 8 h-eighths (48 dwords = 96 h each); per-lane f32 accums, LDS
//  atomic partial reduce, coalesced stores. No cross-lane shuffles.
__global__ __launch_bounds__(512) void corres_kernel(
        const unsigned int* __restrict__ AC16,
        const unsigned int* __restrict__ wg16,
        const float* __restrict__ b_gc,
        const float* __restrict__ rh,
        const float* __restrict__ W_rj, const float* __restrict__ b_rj,
        float* __restrict__ out, float* __restrict__ out_stage1) {
    const int b = blockIdx.y;
    const int tid = threadIdx.x;

    if (blockIdx.x == 32) {
        __shared__ float rl[H2D];
        __shared__ float spart[8][RD];
        if (tid < H2D) rl[tid] = rh[b * H2D + tid];
        __syncthreads();
        if (tid < 8 * RD) {
            const int n = tid % RD, kc = tid / RD;
            float acc = 0.f;
#pragma unroll 8
            for (int i = 0; i < 48; ++i) {
                const int k = kc * 48 + i;
                acc += rl[k] * W_rj[k * RD + n];
            }
            spart[kc][n] = acc;
        }
        __syncthreads();
        if (tid < RD) {
            float s = b_rj[tid];
#pragma unroll
            for (int q = 0; q < 8; ++q) s += spart[q][tid];
            out_stage1[b * RD + tid] = s;
        }
        return;
    }

    const int xt = blockIdx.x >> 1;       // 0..15 -> 8 C-rows each
    const int yg = blockIdx.x & 1;        // 0..1  -> 64 A-rows each
    const int X0 = xt * 8, Y0 = yg * 64;
    const int lane = tid & 63;
    const int w8 = tid >> 6;              // h-eighth 0..7

    __shared__ float lds_out[8][64];
    lds_out[w8][lane] = 0.f;

    // per-lane A-chunk (row Y0+lane, 48 dwords = 96 h) + wg chunk
    f16x2 av[48], wv[48];
    {
        const uint4* ap = (const uint4*)(AC16 + ((size_t)(b * LD + Y0 + lane)) * 768 + w8 * 48);
        const uint4* wp = (const uint4*)(wg16 + w8 * 48);
#pragma unroll
        for (int k = 0; k < 12; ++k) {
            const uint4 va = ap[k];
            const uint4 vw = wp[k];
            av[4*k+0] = __builtin_bit_cast(f16x2, va.x);
            av[4*k+1] = __builtin_bit_cast(f16x2, va.y);
            av[4*k+2] = __builtin_bit_cast(f16x2, va.z);
            av[4*k+3] = __builtin_bit_cast(f16x2, va.w);
            wv[4*k+0] = __builtin_bit_cast(f16x2, vw.x);
            wv[4*k+1] = __builtin_bit_cast(f16x2, vw.y);
            wv[4*k+2] = __builtin_bit_cast(f16x2, vw.z);
            wv[4*k+3] = __builtin_bit_cast(f16x2, vw.w);
        }
    }
    __syncthreads();

    float acc[8];
#pragma unroll
    for (int x = 0; x < 8; ++x) acc[x] = 0.f;

    // C+bc rows are wave-uniform: C-half dwords start at +384; row stride 192 uint4
    const uint4* cbase = (const uint4*)(AC16 + ((size_t)(b * LD + X0)) * 768 + 384 + w8 * 48);
    uint4 cc[12];
#pragma unroll
    for (int k = 0; k < 12; ++k) cc[k] = cbase[k];

#pragma unroll
    for (int x = 0; x < 8; ++x) {
        uint4 nn[12];
        if (x < 7) {
            const uint4* np = cbase + (size_t)(x + 1) * 192;
#pragma unroll
            for (int k = 0; k < 12; ++k) nn[k] = np[k];
        }
        float a = acc[x];
#pragma unroll
        for (int k = 0; k < 12; ++k) {
            dstep(a, cc[k].x, av[4*k+0], wv[4*k+0]);
            dstep(a, cc[k].y, av[4*k+1], wv[4*k+1]);
            dstep(a, cc[k].z, av[4*k+2], wv[4*k+2]);
            dstep(a, cc[k].w, av[4*k+3], wv[4*k+3]);
        }
        acc[x] = a;
        if (x < 7) {
#pragma unroll
            for (int k = 0; k < 12; ++k) cc[k] = nn[k];
        }
    }

#pragma unroll
    for (int x = 0; x < 8; ++x) atomicAdd(&lds_out[x][lane], acc[x]);
    __syncthreads();
    {
        const int xo = tid >> 6, yo = tid & 63;
        out[((size_t)(b * LD + X0 + xo)) * LD + Y0 + yo] = lds_out[xo][yo] + b_gc[0];
    }
}

// ---------------------------------------------------------------------------
extern "C" void kernel_launch(void* const* d_in, const int* in_sizes, int n_in,
                              void* d_out, int out_size, void* d_ws, size_t ws_size,
                              hipStream_t stream) {
    const float* embed   = (const float*)d_in[0];
    const float* mask    = (const float*)d_in[1];
    const int*   trel    = (const int*)d_in[2];
    const float* W_hr    = (const float*)d_in[3];
    const float* b_hr    = (const float*)d_in[4];
    const float* W_rj    = (const float*)d_in[5];
    const float* b_rj    = (const float*)d_in[6];
    const float* rel_emb = (const float*)d_in[7];
    const float* W_corr  = (const float*)d_in[8];
    const float* b_corr  = (const float*)d_in[9];
    const float* W_gc    = (const float*)d_in[10];
    const float* b_gc    = (const float*)d_in[11];
    const float* W_sh    = (const float*)d_in[12];
    const float* b_sh    = (const float*)d_in[13];
    const float* W_st    = (const float*)d_in[14];
    const float* b_st    = (const float*)d_in[15];
    const float* W_oh    = (const float*)d_in[16];
    const float* b_oh    = (const float*)d_in[17];
    const float* W_ot    = (const float*)d_in[18];
    const float* b_ot    = (const float*)d_in[19];
    float* out = (float*)d_out;

    float* ws = (float*)d_ws;
    unsigned int* AC16 = (unsigned int*)ws;                  // 786,432 dwords (1024 x 768)
    float* biasrel = ws + 786432;                            // 12,288
    float* rh      = ws + 786432 + 12288;                    // 3,072
    float* pool    = ws + 786432 + 12288 + 3072;             // 6,144
    unsigned int* wg16 = (unsigned int*)(ws + 807936);       // 384 dwords
    unsigned short* embedB = (unsigned short*)(ws + 808320);           // 786,432 shorts
    unsigned short* WT     = (unsigned short*)(ws + 808320 + 393216);  // 4*589,824 shorts

    // Output layout: stage1[192] | subj[3072] | obj[3072] | pred_corres[131072]
    float* out_stage1 = out;
    float* out_subj   = out + 192;
    float* out_obj    = out + 3264;
    float* out_corr   = out + 6336;

    prep_kernel<<<793, 256, 0, stream>>>(embed, mask, rel_emb, trel, W_corr,
                                         W_sh, b_sh, W_oh, b_oh, b_st, b_ot, W_gc,
                                         pool, biasrel, embedB, WT, wg16,
                                         out_subj, out_obj);

    biggemm<<<dim3(27, 16), 256, 0, stream>>>(embedB, WT, biasrel, W_st, W_ot,
                                              pool, W_hr, b_hr, b_corr,
                                              AC16, out_subj, out_obj, rh);

    corres_kernel<<<dim3(33, BD), 512, 0, stream>>>(AC16, wg16, b_gc,
                                                    rh, W_rj, b_rj, out_corr, out_stage1);
}

// Round 3
// 152.889 us; speedup vs baseline: 1.0553x; 1.0058x over previous
//
#include <hip/hip_runtime.h>
#include <hip/hip_bf16.h>

// Problem dims (fixed): B=8, L=128, H=768, R=24
#define BD   8
#define LD   128
#define HD   768
#define RD   24
#define H2D  384
#define NF   1536   // fused N (two heads side by side)
#define WSZ  589824 // 768*768

typedef __attribute__((ext_vector_type(8))) short bf16x8;
typedef __attribute__((ext_vector_type(4))) float f32x4;
typedef _Float16 f16x2 __attribute__((ext_vector_type(2)));

__device__ __forceinline__ short f2bf(float f) {
    __hip_bfloat16 h = __float2bfloat16(f);
    return *reinterpret_cast<short*>(&h);
}

// pack two f32 -> one dword of two f16 (RNE)
__device__ __forceinline__ unsigned int packh2(float a, float b) {
    f16x2 p;
    p[0] = (_Float16)a;
    p[1] = (_Float16)b;
    return __builtin_bit_cast(unsigned int, p);
}

// acc += dot2(relu(a + c), w)  -- packed f16 pair math, f32 accumulate
__device__ __forceinline__ void dstep(float& acc, unsigned int cu, f16x2 a, f16x2 w) {
    f16x2 t = a + __builtin_bit_cast(f16x2, cu);
    f16x2 z = {(_Float16)0.f, (_Float16)0.f};
    t = __builtin_elementwise_max(t, z);
#if __has_builtin(__builtin_amdgcn_fdot2)
    acc = __builtin_amdgcn_fdot2(t, w, acc, false);
#else
    acc += (float)t[0] * (float)w[0] + (float)t[1] * (float)w[1];
#endif
}

// async global -> LDS, 16B per lane, wave-uniform LDS base + lane*16
typedef const __attribute__((address_space(1))) unsigned int* as1_u32p;
typedef __attribute__((address_space(3))) unsigned int* as3_u32p;
__device__ __forceinline__ void gload16(const void* g, void* l) {
    __builtin_amdgcn_global_load_lds((as1_u32p)g, (as3_u32p)l, 16, 0, 0);
}

// raw workgroup barrier with compiler fences (no vmcnt/lgkm drain)
__device__ __forceinline__ void block_sync() {
    asm volatile("" ::: "memory");
    __builtin_amdgcn_sched_barrier(0);
    __builtin_amdgcn_s_barrier();
    __builtin_amdgcn_sched_barrier(0);
    asm volatile("" ::: "memory");
}

// ---------------------------------------------------------------------------
// Launch 1: prep. 793 blocks x 256 threads, flat blockIdx.x:
//   [0,96):    pool
//   [96,120):  biasrel (+ subj/obj bias init on q==96)
//   [120,216): embed fp32 -> bf16 (row-major)
//   [216,792): W 64x64 tile transpose+convert
//   792:       wg16 pack: wg16[d] = pack(W_gc[n], W_gc[n+16]), n=(d&15)+(d>>4)*32
__global__ __launch_bounds__(256) void prep_kernel(
        const float* __restrict__ embed, const float* __restrict__ mask,
        const float* __restrict__ rel_emb, const int* __restrict__ trel,
        const float* __restrict__ W_corr,
        const float* __restrict__ W_sh, const float* __restrict__ b_sh,
        const float* __restrict__ W_oh, const float* __restrict__ b_oh,
        const float* __restrict__ b_st, const float* __restrict__ b_ot,
        const float* __restrict__ W_gc,
        float* __restrict__ pool, float* __restrict__ biasrel,
        unsigned short* __restrict__ embedB, unsigned short* __restrict__ WT,
        unsigned int* __restrict__ wg16,
        float* __restrict__ out_subj, float* __restrict__ out_obj) {
    const int q = blockIdx.x, tid = threadIdx.x;

    if (q < 96) {
        // ---- pool
        const int b = q / 12, c = q % 12;
        __shared__ float mrow[LD];
        __shared__ float msum;
        __shared__ float part[4][64];
        if (tid < LD) mrow[tid] = mask[b * LD + tid];
        __syncthreads();
        if (tid == 0) {
            float s = 0.f;
            for (int l = 0; l < LD; ++l) s += mrow[l];
            msum = s;
        }
        __syncthreads();
        const int lc = tid >> 6, hh = tid & 63;
        const int h = c * 64 + hh;
        float acc = 0.f;
        const float* base = embed + ((size_t)b * LD + lc * 32) * HD + h;
#pragma unroll 8
        for (int i = 0; i < 32; ++i) acc += base[(size_t)i * HD] * mrow[lc * 32 + i];
        part[lc][hh] = acc;
        __syncthreads();
        if (lc == 0)
            pool[b * HD + h] = (part[0][hh] + part[1][hh] + part[2][hh] + part[3][hh]) / msum;
    } else if (q < 120) {
        // ---- biasrel: block c handles 64 cols for ALL 8 batches
        const int c = q - 96;             // 0..23
        __shared__ float reAll[8][HD];    // 24.6 KB
        __shared__ float part[4][8][64];  // 8 KB
        for (int u = tid; u < 8 * HD; u += 256) {
            const int b = u / HD, k = u - b * HD;
            reAll[b][k] = rel_emb[(size_t)trel[b] * HD + k];
        }
        if (c == 0) {
            for (int u = tid; u < 3 * LD * BD; u += 256) {
                const int b = u / (3 * LD), rem = u - b * (3 * LD);
                const int l = rem / 3, t = rem - 3 * l;
                out_subj[(b * LD + l) * 3 + t] = b_st[t];
                out_obj [(b * LD + l) * 3 + t] = b_ot[t];
            }
        }
        __syncthreads();
        const int kc = tid >> 6, nn = tid & 63;
        const int n = c * 64 + nn;
        const float* Wp; int col;
        if (n < HD) { Wp = W_sh; col = n; }
        else        { Wp = W_oh; col = n - HD; }
        float acc[8] = {};
        for (int i = 0; i < 192; ++i) {
            const int k = kc * 192 + i;
            const float w = Wp[(size_t)k * HD + col];
#pragma unroll
            for (int b = 0; b < 8; ++b) acc[b] += reAll[b][k] * w;
        }
#pragma unroll
        for (int b = 0; b < 8; ++b) part[kc][b][nn] = acc[b];
        __syncthreads();
        {
            const float bb = (n < HD) ? b_sh[col] : b_oh[col];
            const int b0 = kc, b1 = kc + 4;
            float s0 = part[0][b0][nn] + part[1][b0][nn] + part[2][b0][nn] + part[3][b0][nn];
            float s1 = part[0][b1][nn] + part[1][b1][nn] + part[2][b1][nn] + part[3][b1][nn];
            biasrel[b0 * NF + n] = s0 + bb;
            biasrel[b1 * NF + n] = s1 + bb;
        }
    } else if (q < 216) {
        // ---- embed convert (row-major): 8192 elems per block
        const int base = (q - 120) * 8192;
#pragma unroll
        for (int it = 0; it < 4; ++it) {
            const int off = base + it * 2048 + tid * 8;
            float4 v0 = *(const float4*)&embed[off];
            float4 v1 = *(const float4*)&embed[off + 4];
            bf16x8 p;
            p[0] = f2bf(v0.x); p[1] = f2bf(v0.y); p[2] = f2bf(v0.z); p[3] = f2bf(v0.w);
            p[4] = f2bf(v1.x); p[5] = f2bf(v1.y); p[6] = f2bf(v1.z); p[7] = f2bf(v1.w);
            *(bf16x8*)&embedB[off] = p;
        }
    } else if (q < 792) {
        // ---- W transpose+convert, one 64x64 tile per block
        const int qq = q - 216;
        const int w = qq / 144, t = qq % 144;
        const int kt = t / 12, nt = t % 12;
        const float* src = (w == 0) ? W_corr
                         : (w == 1) ? W_corr + WSZ
                         : (w == 2) ? W_sh + WSZ
                                    : W_oh + WSZ;
        unsigned short* dst = WT + (size_t)w * WSZ;
        __shared__ float tile[64 * 65];
        const int r = tid >> 2, c4 = (tid & 3) * 16;
#pragma unroll
        for (int i = 0; i < 4; ++i) {
            float4 v = *(const float4*)&src[(size_t)(kt * 64 + r) * HD + nt * 64 + c4 + i * 4];
            tile[r * 65 + c4 + i * 4 + 0] = v.x;
            tile[r * 65 + c4 + i * 4 + 1] = v.y;
            tile[r * 65 + c4 + i * 4 + 2] = v.z;
            tile[r * 65 + c4 + i * 4 + 3] = v.w;
        }
        __syncthreads();
        bf16x8 p0, p1;
#pragma unroll
        for (int j = 0; j < 8; ++j) {
            p0[j] = f2bf(tile[(c4 + j) * 65 + r]);
            p1[j] = f2bf(tile[(c4 + 8 + j) * 65 + r]);
        }
        unsigned short* o = dst + (size_t)(nt * 64 + r) * HD + kt * 64 + c4;
        *(bf16x8*)(o)     = p0;
        *(bf16x8*)(o + 8) = p1;
    } else {
        // ---- wg16 pack (q == 792): 384 entries, 256 threads -> grid-stride
        for (int u = tid; u < 384; u += 256) {
            const int n = (u & 15) + (u >> 4) * 32;
            wg16[u] = packh2(W_gc[n], W_gc[n + 16]);
        }
    }
}

// ---------------------------------------------------------------------------
// Launch 2: biggemm. grid (27, 16), 256 threads.
//  x < 24: dual MFMA GEMM, T3-minimum pipeline:
//    double-buffered LDS, global_load_lds width-16 staging (linear LDS dest,
//    XOR-swizzled global source: colbyte ^= ((row&7)<<4)), swizzled ds_read,
//    ONE raw barrier + vmcnt(0) per K-tile.
//  x >= 24: relh blocks (48)
__global__ __launch_bounds__(256) void biggemm(
        const unsigned short* __restrict__ embedB,
        const unsigned short* __restrict__ WT,
        const float* __restrict__ biasrel,
        const float* __restrict__ W_st, const float* __restrict__ W_ot,
        const float* __restrict__ pool,
        const float* __restrict__ W_hr, const float* __restrict__ b_hr,
        const float* __restrict__ b_corr,
        unsigned int* __restrict__ AC16, float* __restrict__ out_subj,
        float* __restrict__ out_obj, float* __restrict__ rh) {
    const int tid = threadIdx.x;

    if (blockIdx.x >= 24) {
        const int b = blockIdx.y >> 1;
        const int c = (blockIdx.x - 24) * 2 + (blockIdx.y & 1);
        __shared__ float prow[HD];
        __shared__ float rpart[4][64];
        for (int k = tid; k < HD; k += 256) prow[k] = pool[b * HD + k];
        __syncthreads();
        const int kc = tid >> 6, nn = tid & 63;
        const int n = c * 64 + nn;
        float acc = 0.f;
#pragma unroll 8
        for (int i = 0; i < 192; ++i) {
            const int k = kc * 192 + i;
            acc += prow[k] * W_hr[(size_t)k * H2D + n];
        }
        rpart[kc][nn] = acc;
        __syncthreads();
        if (kc == 0)
            rh[b * H2D + n] = fmaxf(rpart[0][nn] + rpart[1][nn] + rpart[2][nn] + rpart[3][nn] + b_hr[n], 0.f);
        return;
    }

    // double-buffered linear LDS: [buf][matrix][row][64 shorts] (48 KB)
    __shared__ __align__(16) short ldsb[2][3][64][64];
    __shared__ float partial[64][3];

    const int bn0 = blockIdx.x * 64;
    const int bm0 = blockIdx.y * 64;

    const unsigned short* W0 = (bn0 < HD) ? WT : WT + WSZ;
    const unsigned short* W1 = (bn0 < HD) ? WT + 2 * (size_t)WSZ : WT + 3 * (size_t)WSZ;
    const int col0 = (bn0 < HD) ? bn0 : bn0 - HD;

    if (tid < 192) partial[tid / 3][tid % 3] = 0.f;

    const int lane = tid & 63;
    const int wv = tid >> 6;
    const int wm = (wv >> 1) * 32;
    const int wn = (wv & 1) * 32;
    const int fr = lane & 15;
    const int mq = (lane >> 4) * 4;

    // staging geometry: wave wv handles segments {2wv, 2wv+1}; within a segment,
    // lane covers row = seg*8 + (lane>>3), 16B chunk ((lane&7)^(lane>>3))*16.
    const int g8  = lane >> 3;
    const int xsw = ((lane & 7) ^ g8) << 3;      // global col offset, shorts
    // read-side swizzle for row wm/wn + fr (+0/+16): (row&7) == (fr&7)
    const int sw = (fr & 7) << 4;                // byte XOR within 128B row

    f32x4 c00 = {0.f,0.f,0.f,0.f}, c01 = c00, c10 = c00, c11 = c00;
    f32x4 h00 = c00, h01 = c00, h10 = c00, h11 = c00;

    auto stage = [&](int kt, int bsel) {
#pragma unroll
        for (int j = 0; j < 2; ++j) {
            const int seg = wv * 2 + j;
            const size_t gofs = (size_t)(seg * 8 + g8) * HD + (kt << 6) + xsw;
            gload16(embedB + (size_t)bm0 * HD + gofs, &ldsb[bsel][0][seg * 8][0]);
            gload16(W0 + (size_t)col0 * HD + gofs,    &ldsb[bsel][1][seg * 8][0]);
            gload16(W1 + (size_t)col0 * HD + gofs,    &ldsb[bsel][2][seg * 8][0]);
        }
    };

    auto compute = [&](int bsel) {
        const char* base0 = (const char*)&ldsb[bsel][0][0][0];
        const char* base1 = (const char*)&ldsb[bsel][1][0][0];
        const char* base2 = (const char*)&ldsb[bsel][2][0][0];
#pragma unroll
        for (int kk = 0; kk < 2; ++kk) {
            const int kx2 = (((lane >> 4) * 16 + kk * 64)) ^ sw;   // byte offset in row
            bf16x8 a0 = *(const bf16x8*)(base0 + (wm + fr) * 128 + kx2);
            bf16x8 a1 = *(const bf16x8*)(base0 + (wm + 16 + fr) * 128 + kx2);
            bf16x8 b0 = *(const bf16x8*)(base1 + (wn + fr) * 128 + kx2);
            bf16x8 b1 = *(const bf16x8*)(base1 + (wn + 16 + fr) * 128 + kx2);
            bf16x8 d0 = *(const bf16x8*)(base2 + (wn + fr) * 128 + kx2);
            bf16x8 d1 = *(const bf16x8*)(base2 + (wn + 16 + fr) * 128 + kx2);
            c00 = __builtin_amdgcn_mfma_f32_16x16x32_bf16(a0, b0, c00, 0, 0, 0);
            c01 = __builtin_amdgcn_mfma_f32_16x16x32_bf16(a0, b1, c01, 0, 0, 0);
            c10 = __builtin_amdgcn_mfma_f32_16x16x32_bf16(a1, b0, c10, 0, 0, 0);
            c11 = __builtin_amdgcn_mfma_f32_16x16x32_bf16(a1, b1, c11, 0, 0, 0);
            h00 = __builtin_amdgcn_mfma_f32_16x16x32_bf16(a0, d0, h00, 0, 0, 0);
            h01 = __builtin_amdgcn_mfma_f32_16x16x32_bf16(a0, d1, h01, 0, 0, 0);
            h10 = __builtin_amdgcn_mfma_f32_16x16x32_bf16(a1, d0, h10, 0, 0, 0);
            h11 = __builtin_amdgcn_mfma_f32_16x16x32_bf16(a1, d1, h11, 0, 0, 0);
        }
    };

    // prologue: tile 0 -> buf 0
    stage(0, 0);
    asm volatile("s_waitcnt vmcnt(0)" ::: "memory");
    block_sync();

    int cur = 0;
    for (int kt = 0; kt < 11; ++kt) {
        stage(kt + 1, cur ^ 1);   // async loads hide under MFMAs below
        compute(cur);
        asm volatile("s_waitcnt vmcnt(0)" ::: "memory");
        block_sync();             // next tile landed; everyone done with buf[cur]
        cur ^= 1;
    }
    compute(cur);                 // tile 11

    // GEMM0 epilogue: pack (col, col+16) pairs from (j=0, j=1) frags in-lane.
    // dword index d = (n&15) + (n>>5)*16; C-half gets +b_corr before pack.
    {
        const int dbase = ((bn0 + wn) >> 5) << 4;
        float bc0 = 0.f, bc1 = 0.f;
        if (bn0 >= HD) {
            bc0 = b_corr[bn0 + wn + fr - HD];
            bc1 = b_corr[bn0 + wn + fr - HD + 16];
        }
#pragma unroll
        for (int i = 0; i < 2; ++i) {
            f32x4 a0 = (i == 0) ? c00 : c10;   // j = 0 frag
            f32x4 a1 = (i == 0) ? c01 : c11;   // j = 1 frag (cols +16)
#pragma unroll
            for (int r = 0; r < 4; ++r) {
                const int mrow = bm0 + wm + i * 16 + mq + r;
                AC16[(size_t)mrow * 768 + dbase + fr] = packh2(a0[r] + bc0, a1[r] + bc1);
            }
        }
    }

    // GEMM1 epilogue: relu(+biasrel), row-dot W_st/W_ot, atomics
    {
        const float* brl = biasrel + (size_t)(bm0 / LD) * NF;
        const float* Wt = (bn0 < HD) ? W_st : W_ot;
        float* op = (bn0 < HD) ? out_subj : out_obj;
        float pt[8][3] = {};
#pragma unroll
        for (int j = 0; j < 2; ++j) {
            const int ncol = bn0 + wn + j * 16 + fr;
            const int ncl = (bn0 < HD) ? ncol : ncol - HD;
            const float wt0 = Wt[ncl * 3 + 0];
            const float wt1 = Wt[ncl * 3 + 1];
            const float wt2 = Wt[ncl * 3 + 2];
            const float bias = brl[ncol];
#pragma unroll
            for (int i = 0; i < 2; ++i) {
                f32x4 a = (i == 0) ? (j == 0 ? h00 : h01) : (j == 0 ? h10 : h11);
#pragma unroll
                for (int r = 0; r < 4; ++r) {
                    const float v = fmaxf(a[r] + bias, 0.f);
                    pt[i * 4 + r][0] += v * wt0;
                    pt[i * 4 + r][1] += v * wt1;
                    pt[i * 4 + r][2] += v * wt2;
                }
            }
        }
#pragma unroll
        for (int mask = 1; mask < 16; mask <<= 1) {
#pragma unroll
            for (int x = 0; x < 8; ++x)
#pragma unroll
                for (int t = 0; t < 3; ++t)
                    pt[x][t] += __shfl_xor(pt[x][t], mask, 64);
        }
        __syncthreads();
        if (fr == 0) {
#pragma unroll
            for (int i = 0; i < 2; ++i)
#pragma unroll
                for (int r = 0; r < 4; ++r)
#pragma unroll
                    for (int t = 0; t < 3; ++t)
                        atomicAdd(&partial[wm + i * 16 + mq + r][t], pt[i * 4 + r][t]);
        }
        __syncthreads();
        if (tid < 192) {
            const int m = tid / 3, t = tid % 3;
            atomicAdd(&op[(size_t)(bm0 + m) * 3 + t], partial[m][t]);
        }
    }
}

// ---------------------------------------------------------------------------
// Launch 3: corres + stage1. grid (33, 8), 512 threads.
//  blockIdx.x < 32: xt = x>>1 (8 C-rows), yg = x&1 (64 A-rows, lane = y).
//  8 waves = 8 h-eighths (48 dwords = 96 h each); per-lane f32 accums, LDS
//  atomic partial reduce, coalesced stores. No cross-lane shuffles.
__global__ __launch_bounds__(512) void corres_kernel(
        const unsigned int* __restrict__ AC16,
        const unsigned int* __restrict__ wg16,
        const float* __restrict__ b_gc,
        const float* __restrict__ rh,
        const float* __restrict__ W_rj, const float* __restrict__ b_rj,
        float* __restrict__ out, float* __restrict__ out_stage1) {
    const int b = blockIdx.y;
    const int tid = threadIdx.x;

    if (blockIdx.x == 32) {
        __shared__ float rl[H2D];
        __shared__ float spart[8][RD];
        if (tid < H2D) rl[tid] = rh[b * H2D + tid];
        __syncthreads();
        if (tid < 8 * RD) {
            const int n = tid % RD, kc = tid / RD;
            float acc = 0.f;
#pragma unroll 8
            for (int i = 0; i < 48; ++i) {
                const int k = kc * 48 + i;
                acc += rl[k] * W_rj[k * RD + n];
            }
            spart[kc][n] = acc;
        }
        __syncthreads();
        if (tid < RD) {
            float s = b_rj[tid];
#pragma unroll
            for (int q = 0; q < 8; ++q) s += spart[q][tid];
            out_stage1[b * RD + tid] = s;
        }
        return;
    }

    const int xt = blockIdx.x >> 1;       // 0..15 -> 8 C-rows each
    const int yg = blockIdx.x & 1;        // 0..1  -> 64 A-rows each
    const int X0 = xt * 8, Y0 = yg * 64;
    const int lane = tid & 63;
    const int w8 = tid >> 6;              // h-eighth 0..7

    __shared__ float lds_out[8][64];
    lds_out[w8][lane] = 0.f;

    // per-lane A-chunk (row Y0+lane, 48 dwords = 96 h) + wg chunk
    f16x2 av[48], wv[48];
    {
        const uint4* ap = (const uint4*)(AC16 + ((size_t)(b * LD + Y0 + lane)) * 768 + w8 * 48);
        const uint4* wp = (const uint4*)(wg16 + w8 * 48);
#pragma unroll
        for (int k = 0; k < 12; ++k) {
            const uint4 va = ap[k];
            const uint4 vw = wp[k];
            av[4*k+0] = __builtin_bit_cast(f16x2, va.x);
            av[4*k+1] = __builtin_bit_cast(f16x2, va.y);
            av[4*k+2] = __builtin_bit_cast(f16x2, va.z);
            av[4*k+3] = __builtin_bit_cast(f16x2, va.w);
            wv[4*k+0] = __builtin_bit_cast(f16x2, vw.x);
            wv[4*k+1] = __builtin_bit_cast(f16x2, vw.y);
            wv[4*k+2] = __builtin_bit_cast(f16x2, vw.z);
            wv[4*k+3] = __builtin_bit_cast(f16x2, vw.w);
        }
    }
    __syncthreads();

    float acc[8];
#pragma unroll
    for (int x = 0; x < 8; ++x) acc[x] = 0.f;

    // C+bc rows are wave-uniform: C-half dwords start at +384; row stride 192 uint4
    const uint4* cbase = (const uint4*)(AC16 + ((size_t)(b * LD + X0)) * 768 + 384 + w8 * 48);
    uint4 cc[12];
#pragma unroll
    for (int k = 0; k < 12; ++k) cc[k] = cbase[k];

#pragma unroll
    for (int x = 0; x < 8; ++x) {
        uint4 nn[12];
        if (x < 7) {
            const uint4* np = cbase + (size_t)(x + 1) * 192;
#pragma unroll
            for (int k = 0; k < 12; ++k) nn[k] = np[k];
        }
        float a = acc[x];
#pragma unroll
        for (int k = 0; k < 12; ++k) {
            dstep(a, cc[k].x, av[4*k+0], wv[4*k+0]);
            dstep(a, cc[k].y, av[4*k+1], wv[4*k+1]);
            dstep(a, cc[k].z, av[4*k+2], wv[4*k+2]);
            dstep(a, cc[k].w, av[4*k+3], wv[4*k+3]);
        }
        acc[x] = a;
        if (x < 7) {
#pragma unroll
            for (int k = 0; k < 12; ++k) cc[k] = nn[k];
        }
    }

#pragma unroll
    for (int x = 0; x < 8; ++x) atomicAdd(&lds_out[x][lane], acc[x]);
    __syncthreads();
    {
        const int xo = tid >> 6, yo = tid & 63;
        out[((size_t)(b * LD + X0 + xo)) * LD + Y0 + yo] = lds_out[xo][yo] + b_gc[0];
    }
}

// ---------------------------------------------------------------------------
extern "C" void kernel_launch(void* const* d_in, const int* in_sizes, int n_in,
                              void* d_out, int out_size, void* d_ws, size_t ws_size,
                              hipStream_t stream) {
    const float* embed   = (const float*)d_in[0];
    const float* mask    = (const float*)d_in[1];
    const int*   trel    = (const int*)d_in[2];
    const float* W_hr    = (const float*)d_in[3];
    const float* b_hr    = (const float*)d_in[4];
    const float* W_rj    = (const float*)d_in[5];
    const float* b_rj    = (const float*)d_in[6];
    const float* rel_emb = (const float*)d_in[7];
    const float* W_corr  = (const float*)d_in[8];
    const float* b_corr  = (const float*)d_in[9];
    const float* W_gc    = (const float*)d_in[10];
    const float* b_gc    = (const float*)d_in[11];
    const float* W_sh    = (const float*)d_in[12];
    const float* b_sh    = (const float*)d_in[13];
    const float* W_st    = (const float*)d_in[14];
    const float* b_st    = (const float*)d_in[15];
    const float* W_oh    = (const float*)d_in[16];
    const float* b_oh    = (const float*)d_in[17];
    const float* W_ot    = (const float*)d_in[18];
    const float* b_ot    = (const float*)d_in[19];
    float* out = (float*)d_out;

    float* ws = (float*)d_ws;
    unsigned int* AC16 = (unsigned int*)ws;                  // 786,432 dwords (1024 x 768)
    float* biasrel = ws + 786432;                            // 12,288
    float* rh      = ws + 786432 + 12288;                    // 3,072
    float* pool    = ws + 786432 + 12288 + 3072;             // 6,144
    unsigned int* wg16 = (unsigned int*)(ws + 807936);       // 384 dwords
    unsigned short* embedB = (unsigned short*)(ws + 808320);           // 786,432 shorts
    unsigned short* WT     = (unsigned short*)(ws + 808320 + 393216);  // 4*589,824 shorts

    // Output layout: stage1[192] | subj[3072] | obj[3072] | pred_corres[131072]
    float* out_stage1 = out;
    float* out_subj   = out + 192;
    float* out_obj    = out + 3264;
    float* out_corr   = out + 6336;

    prep_kernel<<<793, 256, 0, stream>>>(embed, mask, rel_emb, trel, W_corr,
                                         W_sh, b_sh, W_oh, b_oh, b_st, b_ot, W_gc,
                                         pool, biasrel, embedB, WT, wg16,
                                         out_subj, out_obj);

    biggemm<<<dim3(27, 16), 256, 0, stream>>>(embedB, WT, biasrel, W_st, W_ot,
                                              pool, W_hr, b_hr, b_corr,
                                              AC16, out_subj, out_obj, rh);

    corres_kernel<<<dim3(33, BD), 512, 0, stream>>>(AC16, wg16, b_gc,
                                                    rh, W_rj, b_rj, out_corr, out_stage1);
}

// Round 4
// 150.923 us; speedup vs baseline: 1.0690x; 1.0130x over previous
//
#include <hip/hip_runtime.h>
#include <hip/hip_bf16.h>

// Problem dims (fixed): B=8, L=128, H=768, R=24
#define BD   8
#define LD   128
#define HD   768
#define RD   24
#define H2D  384
#define NF   1536   // fused N (two heads side by side)
#define WSZ  589824 // 768*768

typedef __attribute__((ext_vector_type(8))) short bf16x8;
typedef __attribute__((ext_vector_type(4))) float f32x4;
typedef _Float16 f16x2 __attribute__((ext_vector_type(2)));

__device__ __forceinline__ short f2bf(float f) {
    __hip_bfloat16 h = __float2bfloat16(f);
    return *reinterpret_cast<short*>(&h);
}

// pack two f32 -> one dword of two f16 (RNE)
__device__ __forceinline__ unsigned int packh2(float a, float b) {
    f16x2 p;
    p[0] = (_Float16)a;
    p[1] = (_Float16)b;
    return __builtin_bit_cast(unsigned int, p);
}

// acc += dot2(relu(a + c), w)  -- packed f16 pair math, f32 accumulate
__device__ __forceinline__ void dstep(float& acc, unsigned int cu, f16x2 a, f16x2 w) {
    f16x2 t = a + __builtin_bit_cast(f16x2, cu);
    f16x2 z = {(_Float16)0.f, (_Float16)0.f};
    t = __builtin_elementwise_max(t, z);
#if __has_builtin(__builtin_amdgcn_fdot2)
    acc = __builtin_amdgcn_fdot2(t, w, acc, false);
#else
    acc += (float)t[0] * (float)w[0] + (float)t[1] * (float)w[1];
#endif
}

// async global -> LDS, 16B per lane, wave-uniform LDS base + lane*16
typedef const __attribute__((address_space(1))) unsigned int* as1_u32p;
typedef __attribute__((address_space(3))) unsigned int* as3_u32p;
__device__ __forceinline__ void gload16(const void* g, void* l) {
    __builtin_amdgcn_global_load_lds((as1_u32p)g, (as3_u32p)l, 16, 0, 0);
}

// raw workgroup barrier with compiler fences (no vmcnt/lgkm drain)
__device__ __forceinline__ void block_sync() {
    asm volatile("" ::: "memory");
    __builtin_amdgcn_sched_barrier(0);
    __builtin_amdgcn_s_barrier();
    __builtin_amdgcn_sched_barrier(0);
    asm volatile("" ::: "memory");
}

// ---------------------------------------------------------------------------
// Launch 1: prep. 793 blocks x 256 threads, flat blockIdx.x:
//   [0,96):    pool
//   [96,120):  biasrel (+ subj/obj bias init on q==96)
//   [120,216): embed fp32 -> bf16 (row-major)
//   [216,792): W 64x64 tile transpose+convert
//   792:       wg16 pack: wg16[d] = pack(W_gc[n], W_gc[n+16]), n=(d&15)+(d>>4)*32
__global__ __launch_bounds__(256) void prep_kernel(
        const float* __restrict__ embed, const float* __restrict__ mask,
        const float* __restrict__ rel_emb, const int* __restrict__ trel,
        const float* __restrict__ W_corr,
        const float* __restrict__ W_sh, const float* __restrict__ b_sh,
        const float* __restrict__ W_oh, const float* __restrict__ b_oh,
        const float* __restrict__ b_st, const float* __restrict__ b_ot,
        const float* __restrict__ W_gc,
        float* __restrict__ pool, float* __restrict__ biasrel,
        unsigned short* __restrict__ embedB, unsigned short* __restrict__ WT,
        unsigned int* __restrict__ wg16,
        float* __restrict__ out_subj, float* __restrict__ out_obj) {
    const int q = blockIdx.x, tid = threadIdx.x;

    if (q < 96) {
        // ---- pool
        const int b = q / 12, c = q % 12;
        __shared__ float mrow[LD];
        __shared__ float msum;
        __shared__ float part[4][64];
        if (tid < LD) mrow[tid] = mask[b * LD + tid];
        __syncthreads();
        if (tid == 0) {
            float s = 0.f;
            for (int l = 0; l < LD; ++l) s += mrow[l];
            msum = s;
        }
        __syncthreads();
        const int lc = tid >> 6, hh = tid & 63;
        const int h = c * 64 + hh;
        float acc = 0.f;
        const float* base = embed + ((size_t)b * LD + lc * 32) * HD + h;
#pragma unroll 8
        for (int i = 0; i < 32; ++i) acc += base[(size_t)i * HD] * mrow[lc * 32 + i];
        part[lc][hh] = acc;
        __syncthreads();
        if (lc == 0)
            pool[b * HD + h] = (part[0][hh] + part[1][hh] + part[2][hh] + part[3][hh]) / msum;
    } else if (q < 120) {
        // ---- biasrel: block c handles 64 cols for ALL 8 batches
        const int c = q - 96;             // 0..23
        __shared__ float reAll[8][HD];    // 24.6 KB
        __shared__ float part[4][8][64];  // 8 KB
        for (int u = tid; u < 8 * HD; u += 256) {
            const int b = u / HD, k = u - b * HD;
            reAll[b][k] = rel_emb[(size_t)trel[b] * HD + k];
        }
        if (c == 0) {
            for (int u = tid; u < 3 * LD * BD; u += 256) {
                const int b = u / (3 * LD), rem = u - b * (3 * LD);
                const int l = rem / 3, t = rem - 3 * l;
                out_subj[(b * LD + l) * 3 + t] = b_st[t];
                out_obj [(b * LD + l) * 3 + t] = b_ot[t];
            }
        }
        __syncthreads();
        const int kc = tid >> 6, nn = tid & 63;
        const int n = c * 64 + nn;
        const float* Wp; int col;
        if (n < HD) { Wp = W_sh; col = n; }
        else        { Wp = W_oh; col = n - HD; }
        float acc[8] = {};
        for (int i = 0; i < 192; ++i) {
            const int k = kc * 192 + i;
            const float w = Wp[(size_t)k * HD + col];
#pragma unroll
            for (int b = 0; b < 8; ++b) acc[b] += reAll[b][k] * w;
        }
#pragma unroll
        for (int b = 0; b < 8; ++b) part[kc][b][nn] = acc[b];
        __syncthreads();
        {
            const float bb = (n < HD) ? b_sh[col] : b_oh[col];
            const int b0 = kc, b1 = kc + 4;
            float s0 = part[0][b0][nn] + part[1][b0][nn] + part[2][b0][nn] + part[3][b0][nn];
            float s1 = part[0][b1][nn] + part[1][b1][nn] + part[2][b1][nn] + part[3][b1][nn];
            biasrel[b0 * NF + n] = s0 + bb;
            biasrel[b1 * NF + n] = s1 + bb;
        }
    } else if (q < 216) {
        // ---- embed convert (row-major): 8192 elems per block
        const int base = (q - 120) * 8192;
#pragma unroll
        for (int it = 0; it < 4; ++it) {
            const int off = base + it * 2048 + tid * 8;
            float4 v0 = *(const float4*)&embed[off];
            float4 v1 = *(const float4*)&embed[off + 4];
            bf16x8 p;
            p[0] = f2bf(v0.x); p[1] = f2bf(v0.y); p[2] = f2bf(v0.z); p[3] = f2bf(v0.w);
            p[4] = f2bf(v1.x); p[5] = f2bf(v1.y); p[6] = f2bf(v1.z); p[7] = f2bf(v1.w);
            *(bf16x8*)&embedB[off] = p;
        }
    } else if (q < 792) {
        // ---- W transpose+convert, one 64x64 tile per block
        const int qq = q - 216;
        const int w = qq / 144, t = qq % 144;
        const int kt = t / 12, nt = t % 12;
        const float* src = (w == 0) ? W_corr
                         : (w == 1) ? W_corr + WSZ
                         : (w == 2) ? W_sh + WSZ
                                    : W_oh + WSZ;
        unsigned short* dst = WT + (size_t)w * WSZ;
        __shared__ float tile[64 * 65];
        const int r = tid >> 2, c4 = (tid & 3) * 16;
#pragma unroll
        for (int i = 0; i < 4; ++i) {
            float4 v = *(const float4*)&src[(size_t)(kt * 64 + r) * HD + nt * 64 + c4 + i * 4];
            tile[r * 65 + c4 + i * 4 + 0] = v.x;
            tile[r * 65 + c4 + i * 4 + 1] = v.y;
            tile[r * 65 + c4 + i * 4 + 2] = v.z;
            tile[r * 65 + c4 + i * 4 + 3] = v.w;
        }
        __syncthreads();
        bf16x8 p0, p1;
#pragma unroll
        for (int j = 0; j < 8; ++j) {
            p0[j] = f2bf(tile[(c4 + j) * 65 + r]);
            p1[j] = f2bf(tile[(c4 + 8 + j) * 65 + r]);
        }
        unsigned short* o = dst + (size_t)(nt * 64 + r) * HD + kt * 64 + c4;
        *(bf16x8*)(o)     = p0;
        *(bf16x8*)(o + 8) = p1;
    } else {
        // ---- wg16 pack (q == 792): 384 entries, 256 threads -> grid-stride
        for (int u = tid; u < 384; u += 256) {
            const int n = (u & 15) + (u >> 4) * 32;
            wg16[u] = packh2(W_gc[n], W_gc[n + 16]);
        }
    }
}

// ---------------------------------------------------------------------------
// Launch 2: biggemm. grid (27, 16), 256 threads.
//  x < 24: dual MFMA GEMM, T3+T4 pipeline:
//    TRIPLE-buffered LDS, global_load_lds width-16 staging (linear LDS dest,
//    XOR-swizzled global source), stage 2 tiles ahead, counted vmcnt(6)
//    (never 0 in the main loop), ONE raw barrier per K-tile.
//    vmcnt ledger: 6 loads/lane/stage; at wait point outstanding = {t, t+1}
//    = 12 -> vmcnt(6) retires exactly tile t. stage(t+2) is issued AFTER the
//    barrier, so buf[(t+2)%3] (last read by compute(t-1)) is free.
//  x >= 24: relh blocks (48)
__global__ __launch_bounds__(256) void biggemm(
        const unsigned short* __restrict__ embedB,
        const unsigned short* __restrict__ WT,
        const float* __restrict__ biasrel,
        const float* __restrict__ W_st, const float* __restrict__ W_ot,
        const float* __restrict__ pool,
        const float* __restrict__ W_hr, const float* __restrict__ b_hr,
        const float* __restrict__ b_corr,
        unsigned int* __restrict__ AC16, float* __restrict__ out_subj,
        float* __restrict__ out_obj, float* __restrict__ rh) {
    const int tid = threadIdx.x;

    if (blockIdx.x >= 24) {
        const int b = blockIdx.y >> 1;
        const int c = (blockIdx.x - 24) * 2 + (blockIdx.y & 1);
        __shared__ float prow[HD];
        __shared__ float rpart[4][64];
        for (int k = tid; k < HD; k += 256) prow[k] = pool[b * HD + k];
        __syncthreads();
        const int kc = tid >> 6, nn = tid & 63;
        const int n = c * 64 + nn;
        float acc = 0.f;
#pragma unroll 8
        for (int i = 0; i < 192; ++i) {
            const int k = kc * 192 + i;
            acc += prow[k] * W_hr[(size_t)k * H2D + n];
        }
        rpart[kc][nn] = acc;
        __syncthreads();
        if (kc == 0)
            rh[b * H2D + n] = fmaxf(rpart[0][nn] + rpart[1][nn] + rpart[2][nn] + rpart[3][nn] + b_hr[n], 0.f);
        return;
    }

    // triple-buffered linear LDS: [buf][matrix][row][64 shorts] (72 KB)
    __shared__ __align__(16) short ldsb[3][3][64][64];
    __shared__ float partial[64][3];

    const int bn0 = blockIdx.x * 64;
    const int bm0 = blockIdx.y * 64;

    const unsigned short* W0 = (bn0 < HD) ? WT : WT + WSZ;
    const unsigned short* W1 = (bn0 < HD) ? WT + 2 * (size_t)WSZ : WT + 3 * (size_t)WSZ;
    const int col0 = (bn0 < HD) ? bn0 : bn0 - HD;

    if (tid < 192) partial[tid / 3][tid % 3] = 0.f;

    const int lane = tid & 63;
    const int wv = tid >> 6;
    const int wm = (wv >> 1) * 32;
    const int wn = (wv & 1) * 32;
    const int fr = lane & 15;
    const int mq = (lane >> 4) * 4;

    // staging geometry: wave wv handles segments {2wv, 2wv+1}; within a segment,
    // lane covers row = seg*8 + (lane>>3), 16B chunk ((lane&7)^(lane>>3))*16.
    const int g8  = lane >> 3;
    const int xsw = ((lane & 7) ^ g8) << 3;      // global col offset, shorts
    // read-side swizzle for row wm/wn + fr (+0/+16): (row&7) == (fr&7)
    const int sw = (fr & 7) << 4;                // byte XOR within 128B row

    f32x4 c00 = {0.f,0.f,0.f,0.f}, c01 = c00, c10 = c00, c11 = c00;
    f32x4 h00 = c00, h01 = c00, h10 = c00, h11 = c00;

    auto stage = [&](int kt, int bsel) {
#pragma unroll
        for (int j = 0; j < 2; ++j) {
            const int seg = wv * 2 + j;
            const size_t gofs = (size_t)(seg * 8 + g8) * HD + (kt << 6) + xsw;
            gload16(embedB + (size_t)bm0 * HD + gofs, &ldsb[bsel][0][seg * 8][0]);
            gload16(W0 + (size_t)col0 * HD + gofs,    &ldsb[bsel][1][seg * 8][0]);
            gload16(W1 + (size_t)col0 * HD + gofs,    &ldsb[bsel][2][seg * 8][0]);
        }
    };

    auto compute = [&](int bsel) {
        const char* base0 = (const char*)&ldsb[bsel][0][0][0];
        const char* base1 = (const char*)&ldsb[bsel][1][0][0];
        const char* base2 = (const char*)&ldsb[bsel][2][0][0];
#pragma unroll
        for (int kk = 0; kk < 2; ++kk) {
            const int kx2 = (((lane >> 4) * 16 + kk * 64)) ^ sw;   // byte offset in row
            bf16x8 a0 = *(const bf16x8*)(base0 + (wm + fr) * 128 + kx2);
            bf16x8 a1 = *(const bf16x8*)(base0 + (wm + 16 + fr) * 128 + kx2);
            bf16x8 b0 = *(const bf16x8*)(base1 + (wn + fr) * 128 + kx2);
            bf16x8 b1 = *(const bf16x8*)(base1 + (wn + 16 + fr) * 128 + kx2);
            bf16x8 d0 = *(const bf16x8*)(base2 + (wn + fr) * 128 + kx2);
            bf16x8 d1 = *(const bf16x8*)(base2 + (wn + 16 + fr) * 128 + kx2);
            c00 = __builtin_amdgcn_mfma_f32_16x16x32_bf16(a0, b0, c00, 0, 0, 0);
            c01 = __builtin_amdgcn_mfma_f32_16x16x32_bf16(a0, b1, c01, 0, 0, 0);
            c10 = __builtin_amdgcn_mfma_f32_16x16x32_bf16(a1, b0, c10, 0, 0, 0);
            c11 = __builtin_amdgcn_mfma_f32_16x16x32_bf16(a1, b1, c11, 0, 0, 0);
            h00 = __builtin_amdgcn_mfma_f32_16x16x32_bf16(a0, d0, h00, 0, 0, 0);
            h01 = __builtin_amdgcn_mfma_f32_16x16x32_bf16(a0, d1, h01, 0, 0, 0);
            h10 = __builtin_amdgcn_mfma_f32_16x16x32_bf16(a1, d0, h10, 0, 0, 0);
            h11 = __builtin_amdgcn_mfma_f32_16x16x32_bf16(a1, d1, h11, 0, 0, 0);
        }
    };

    // prologue: tiles 0,1 -> bufs 0,1 (12 loads/lane in flight)
    stage(0, 0);
    stage(1, 1);

    for (int kt = 0; kt < 11; ++kt) {
        asm volatile("s_waitcnt vmcnt(6)" ::: "memory");   // tile kt landed; kt+1 stays in flight
        block_sync();                                      // deposits visible; buf[(kt+2)%3] free
        if (kt < 10) stage(kt + 2, (kt + 2) % 3);
        compute(kt % 3);
    }
    asm volatile("s_waitcnt vmcnt(0)" ::: "memory");       // tile 11 landed
    block_sync();
    compute(11 % 3);

    // GEMM0 epilogue: pack (col, col+16) pairs from (j=0, j=1) frags in-lane.
    // dword index d = (n&15) + (n>>5)*16; C-half gets +b_corr before pack.
    {
        const int dbase = ((bn0 + wn) >> 5) << 4;
        float bc0 = 0.f, bc1 = 0.f;
        if (bn0 >= HD) {
            bc0 = b_corr[bn0 + wn + fr - HD];
            bc1 = b_corr[bn0 + wn + fr - HD + 16];
        }
#pragma unroll
        for (int i = 0; i < 2; ++i) {
            f32x4 a0 = (i == 0) ? c00 : c10;   // j = 0 frag
            f32x4 a1 = (i == 0) ? c01 : c11;   // j = 1 frag (cols +16)
#pragma unroll
            for (int r = 0; r < 4; ++r) {
                const int mrow = bm0 + wm + i * 16 + mq + r;
                AC16[(size_t)mrow * 768 + dbase + fr] = packh2(a0[r] + bc0, a1[r] + bc1);
            }
        }
    }

    // GEMM1 epilogue: relu(+biasrel), row-dot W_st/W_ot, atomics
    {
        const float* brl = biasrel + (size_t)(bm0 / LD) * NF;
        const float* Wt = (bn0 < HD) ? W_st : W_ot;
        float* op = (bn0 < HD) ? out_subj : out_obj;
        float pt[8][3] = {};
#pragma unroll
        for (int j = 0; j < 2; ++j) {
            const int ncol = bn0 + wn + j * 16 + fr;
            const int ncl = (bn0 < HD) ? ncol : ncol - HD;
            const float wt0 = Wt[ncl * 3 + 0];
            const float wt1 = Wt[ncl * 3 + 1];
            const float wt2 = Wt[ncl * 3 + 2];
            const float bias = brl[ncol];
#pragma unroll
            for (int i = 0; i < 2; ++i) {
                f32x4 a = (i == 0) ? (j == 0 ? h00 : h01) : (j == 0 ? h10 : h11);
#pragma unroll
                for (int r = 0; r < 4; ++r) {
                    const float v = fmaxf(a[r] + bias, 0.f);
                    pt[i * 4 + r][0] += v * wt0;
                    pt[i * 4 + r][1] += v * wt1;
                    pt[i * 4 + r][2] += v * wt2;
                }
            }
        }
#pragma unroll
        for (int mask = 1; mask < 16; mask <<= 1) {
#pragma unroll
            for (int x = 0; x < 8; ++x)
#pragma unroll
                for (int t = 0; t < 3; ++t)
                    pt[x][t] += __shfl_xor(pt[x][t], mask, 64);
        }
        __syncthreads();
        if (fr == 0) {
#pragma unroll
            for (int i = 0; i < 2; ++i)
#pragma unroll
                for (int r = 0; r < 4; ++r)
#pragma unroll
                    for (int t = 0; t < 3; ++t)
                        atomicAdd(&partial[wm + i * 16 + mq + r][t], pt[i * 4 + r][t]);
        }
        __syncthreads();
        if (tid < 192) {
            const int m = tid / 3, t = tid % 3;
            atomicAdd(&op[(size_t)(bm0 + m) * 3 + t], partial[m][t]);
        }
    }
}

// ---------------------------------------------------------------------------
// Launch 3: corres + stage1. grid (33, 8), 512 threads.
//  blockIdx.x < 32: xt = x>>1 (8 C-rows), yg = x&1 (64 A-rows, lane = y).
//  8 waves = 8 h-eighths (48 dwords = 96 h each); per-lane f32 accums, LDS
//  atomic partial reduce, coalesced stores. No cross-lane shuffles.
__global__ __launch_bounds__(512) void corres_kernel(
        const unsigned int* __restrict__ AC16,
        const unsigned int* __restrict__ wg16,
        const float* __restrict__ b_gc,
        const float* __restrict__ rh,
        const float* __restrict__ W_rj, const float* __restrict__ b_rj,
        float* __restrict__ out, float* __restrict__ out_stage1) {
    const int b = blockIdx.y;
    const int tid = threadIdx.x;

    if (blockIdx.x == 32) {
        __shared__ float rl[H2D];
        __shared__ float spart[8][RD];
        if (tid < H2D) rl[tid] = rh[b * H2D + tid];
        __syncthreads();
        if (tid < 8 * RD) {
            const int n = tid % RD, kc = tid / RD;
            float acc = 0.f;
#pragma unroll 8
            for (int i = 0; i < 48; ++i) {
                const int k = kc * 48 + i;
                acc += rl[k] * W_rj[k * RD + n];
            }
            spart[kc][n] = acc;
        }
        __syncthreads();
        if (tid < RD) {
            float s = b_rj[tid];
#pragma unroll
            for (int q = 0; q < 8; ++q) s += spart[q][tid];
            out_stage1[b * RD + tid] = s;
        }
        return;
    }

    const int xt = blockIdx.x >> 1;       // 0..15 -> 8 C-rows each
    const int yg = blockIdx.x & 1;        // 0..1  -> 64 A-rows each
    const int X0 = xt * 8, Y0 = yg * 64;
    const int lane = tid & 63;
    const int w8 = tid >> 6;              // h-eighth 0..7

    __shared__ float lds_out[8][64];
    lds_out[w8][lane] = 0.f;

    // per-lane A-chunk (row Y0+lane, 48 dwords = 96 h) + wg chunk
    f16x2 av[48], wv[48];
    {
        const uint4* ap = (const uint4*)(AC16 + ((size_t)(b * LD + Y0 + lane)) * 768 + w8 * 48);
        const uint4* wp = (const uint4*)(wg16 + w8 * 48);
#pragma unroll
        for (int k = 0; k < 12; ++k) {
            const uint4 va = ap[k];
            const uint4 vw = wp[k];
            av[4*k+0] = __builtin_bit_cast(f16x2, va.x);
            av[4*k+1] = __builtin_bit_cast(f16x2, va.y);
            av[4*k+2] = __builtin_bit_cast(f16x2, va.z);
            av[4*k+3] = __builtin_bit_cast(f16x2, va.w);
            wv[4*k+0] = __builtin_bit_cast(f16x2, vw.x);
            wv[4*k+1] = __builtin_bit_cast(f16x2, vw.y);
            wv[4*k+2] = __builtin_bit_cast(f16x2, vw.z);
            wv[4*k+3] = __builtin_bit_cast(f16x2, vw.w);
        }
    }
    __syncthreads();

    float acc[8];
#pragma unroll
    for (int x = 0; x < 8; ++x) acc[x] = 0.f;

    // C+bc rows are wave-uniform: C-half dwords start at +384; row stride 192 uint4
    const uint4* cbase = (const uint4*)(AC16 + ((size_t)(b * LD + X0)) * 768 + 384 + w8 * 48);
    uint4 cc[12];
#pragma unroll
    for (int k = 0; k < 12; ++k) cc[k] = cbase[k];

#pragma unroll
    for (int x = 0; x < 8; ++x) {
        uint4 nn[12];
        if (x < 7) {
            const uint4* np = cbase + (size_t)(x + 1) * 192;
#pragma unroll
            for (int k = 0; k < 12; ++k) nn[k] = np[k];
        }
        float a = acc[x];
#pragma unroll
        for (int k = 0; k < 12; ++k) {
            dstep(a, cc[k].x, av[4*k+0], wv[4*k+0]);
            dstep(a, cc[k].y, av[4*k+1], wv[4*k+1]);
            dstep(a, cc[k].z, av[4*k+2], wv[4*k+2]);
            dstep(a, cc[k].w, av[4*k+3], wv[4*k+3]);
        }
        acc[x] = a;
        if (x < 7) {
#pragma unroll
            for (int k = 0; k < 12; ++k) cc[k] = nn[k];
        }
    }

#pragma unroll
    for (int x = 0; x < 8; ++x) atomicAdd(&lds_out[x][lane], acc[x]);
    __syncthreads();
    {
        const int xo = tid >> 6, yo = tid & 63;
        out[((size_t)(b * LD + X0 + xo)) * LD + Y0 + yo] = lds_out[xo][yo] + b_gc[0];
    }
}

// ---------------------------------------------------------------------------
extern "C" void kernel_launch(void* const* d_in, const int* in_sizes, int n_in,
                              void* d_out, int out_size, void* d_ws, size_t ws_size,
                              hipStream_t stream) {
    const float* embed   = (const float*)d_in[0];
    const float* mask    = (const float*)d_in[1];
    const int*   trel    = (const int*)d_in[2];
    const float* W_hr    = (const float*)d_in[3];
    const float* b_hr    = (const float*)d_in[4];
    const float* W_rj    = (const float*)d_in[5];
    const float* b_rj    = (const float*)d_in[6];
    const float* rel_emb = (const float*)d_in[7];
    const float* W_corr  = (const float*)d_in[8];
    const float* b_corr  = (const float*)d_in[9];
    const float* W_gc    = (const float*)d_in[10];
    const float* b_gc    = (const float*)d_in[11];
    const float* W_sh    = (const float*)d_in[12];
    const float* b_sh    = (const float*)d_in[13];
    const float* W_st    = (const float*)d_in[14];
    const float* b_st    = (const float*)d_in[15];
    const float* W_oh    = (const float*)d_in[16];
    const float* b_oh    = (const float*)d_in[17];
    const float* W_ot    = (const float*)d_in[18];
    const float* b_ot    = (const float*)d_in[19];
    float* out = (float*)d_out;

    float* ws = (float*)d_ws;
    unsigned int* AC16 = (unsigned int*)ws;                  // 786,432 dwords (1024 x 768)
    float* biasrel = ws + 786432;                            // 12,288
    float* rh      = ws + 786432 + 12288;                    // 3,072
    float* pool    = ws + 786432 + 12288 + 3072;             // 6,144
    unsigned int* wg16 = (unsigned int*)(ws + 807936);       // 384 dwords
    unsigned short* embedB = (unsigned short*)(ws + 808320);           // 786,432 shorts
    unsigned short* WT     = (unsigned short*)(ws + 808320 + 393216);  // 4*589,824 shorts

    // Output layout: stage1[192] | subj[3072] | obj[3072] | pred_corres[131072]
    float* out_stage1 = out;
    float* out_subj   = out + 192;
    float* out_obj    = out + 3264;
    float* out_corr   = out + 6336;

    prep_kernel<<<793, 256, 0, stream>>>(embed, mask, rel_emb, trel, W_corr,
                                         W_sh, b_sh, W_oh, b_oh, b_st, b_ot, W_gc,
                                         pool, biasrel, embedB, WT, wg16,
                                         out_subj, out_obj);

    biggemm<<<dim3(27, 16), 256, 0, stream>>>(embedB, WT, biasrel, W_st, W_ot,
                                              pool, W_hr, b_hr, b_corr,
                                              AC16, out_subj, out_obj, rh);

    corres_kernel<<<dim3(33, BD), 512, 0, stream>>>(AC16, wg16, b_gc,
                                                    rh, W_rj, b_rj, out_corr, out_stage1);
}